// Round 8
// baseline (685.310 us; speedup 1.0000x reference)
//
#include <hip/hip_runtime.h>
#include <math.h>

#define S_ROWS 2047
#define DIM 256
#define NBINS 16
#define AFF_OUT 49

typedef short bf16x8 __attribute__((ext_vector_type(8)));
typedef float f32x4 __attribute__((ext_vector_type(4)));
typedef float f32x16 __attribute__((ext_vector_type(16)));
typedef unsigned short u16x8 __attribute__((ext_vector_type(8)));
typedef unsigned short u16x4 __attribute__((ext_vector_type(4)));

__device__ __forceinline__ unsigned short f2b(float f) {
    unsigned int u = __float_as_uint(f);
    u += 0x7FFFu + ((u >> 16) & 1u);      // round-to-nearest-even
    return (unsigned short)(u >> 16);
}

// bf16 weight region (u16 offsets): [ew0 padded 512x64 | 12 segments]
#define W_MAIN 3957248
#define EW0P_N 32768
#define OFF_EW0 0
#define OFF_EW1 (EW0P_N + 0)
#define OFF_EW2 (EW0P_N + 262144)
#define OFF_WQ  (EW0P_N + 393216)
#define OFF_WK  (EW0P_N + 655360)
#define OFF_WV  (EW0P_N + 917504)
#define OFF_WO  (EW0P_N + 1179648)
#define OFF_MW0 (EW0P_N + 1441792)
#define OFF_MW1 (EW0P_N + 1966080)
#define OFF_MW2 (EW0P_N + 3014656)
#define OFF_AW0 (EW0P_N + 3538944)
#define OFF_AW1 (EW0P_N + 3670016)
#define OFF_AW2 (EW0P_N + 3932160)

struct Args {
    const float *pos, *scale, *press, *temp;
    const float *e_w0;
    const float *wsrc[12];
    const float *e_b0, *e_b1, *e_b2, *bk, *bo;
    const float *mb0, *mb1, *mb2, *a_b0, *a_b1, *a_b2;
    unsigned short *wbp, *cond, *obb, *qbh, *kbh, *vbT;
    float *hbuf, *out;
};

// ---------------------------------------------------------------------------
// setup (proven): weight f32->bf16 (+ew0 pad to K=64), cond embed, pos copy.
// ---------------------------------------------------------------------------
#define SP0 (W_MAIN / 4)
#define SP1 (SP0 + EW0P_N / 4)
#define SP2 (SP1 + 2048 * 64 / 4)
#define SP3 (SP2 + 1537)
__global__ __launch_bounds__(256) void setup_kernel(Args a)
{
    const int offs[13] = {0, 262144, 393216, 655360, 917504, 1179648, 1441792,
                          1966080, 3014656, 3538944, 3670016, 3932160, 3957248};
    for (int i4 = blockIdx.x * 256 + threadIdx.x; i4 < SP3;
         i4 += gridDim.x * 256) {
        if (i4 < SP0) {
            int e = i4 * 4;
            int s = 0;
            #pragma unroll
            for (int j = 1; j < 12; j++) s += (e >= offs[j]);
            const float4 v = *(const float4*)(a.wsrc[s] + (e - offs[s]));
            u16x4 o;
            o[0] = f2b(v.x); o[1] = f2b(v.y); o[2] = f2b(v.z); o[3] = f2b(v.w);
            *(u16x4*)(a.wbp + EW0P_N + e) = o;
        } else if (i4 < SP1) {
            int e = (i4 - SP0) * 4;
            u16x4 o;
            #pragma unroll
            for (int r = 0; r < 4; r++) {
                int ee = e + r;
                int row = ee >> 6, col = ee & 63;
                o[r] = (col < 35) ? f2b(a.e_w0[row * 35 + col]) : (unsigned short)0;
            }
            *(u16x4*)(a.wbp + e) = o;
        } else if (i4 < SP2) {
            int e = (i4 - SP1) * 4;
            int row = e >> 6;
            u16x4 o;
            #pragma unroll
            for (int r = 0; r < 4; r++) {
                int c = (e + r) & 63;
                float v = 0.f;
                if (row < S_ROWS) {
                    if (c < 32) {
                        int coord = c >> 4;
                        int w = c & 15;
                        float x = a.pos[(row + 1) * 3 + coord];
                        float f = 6.283185307179586f * (float)((w & 7) + 1);
                        v = (w < 8) ? cosf(x * f) : sinf(x * f);
                    } else if (c == 32) v = a.scale[0];
                    else if (c == 33) v = a.temp[0];
                    else if (c == 34) v = a.press[0];
                }
                o[r] = f2b(v);
            }
            *(u16x4*)(a.cond + e) = o;
        } else {
            int e = (i4 - SP2) * 4;
            #pragma unroll
            for (int r = 0; r < 4; r++) {
                int ee = e + r;
                if (ee < 6144) a.out[ee] = a.pos[ee];
                else if (ee == 6144) a.out[ee] = 0.f;
            }
        }
    }
}

// ---------------------------------------------------------------------------
// Chain stage v2: block = 16 rows, 4 waves. Weights staged cooperatively in
// LDS 64x64 tiles (identical mechanics/indexing to the proven ~5us gemm),
// register prefetch of next tile; wave w MFMAs cols [c0+16w, c0+16w+16).
// ---------------------------------------------------------------------------
#define LDA 520        // u16 stride of LDS activation buffers
#define LDH 260        // f32 stride of LDS residual buffer
#define M_RELU 0
#define M_HBI  1       // hbL = v; OL = bf16(v)
#define M_RES  2       // v += hbL; hbL = v; OL = bf16(v)
#define M_Q    3
#define M_K    4
#define M_V    5
#define M_F32  6       // f32 -> hbL (spline params), guard col < 49

template<int KIN, int MOUT, int MODE>
__device__ __forceinline__ void stage2(
    const unsigned short* __restrict__ AL, unsigned short* __restrict__ wst,
    const unsigned short* __restrict__ Wg, const float* __restrict__ biasG,
    unsigned short* __restrict__ OL, float* __restrict__ hbL,
    unsigned short* __restrict__ qkvG, const float* __restrict__ bkG,
    int rowBase, int tid)
{
    int wave = tid >> 6, lane = tid & 63, quad = lane >> 4, l16 = lane & 15;
    int sr = tid >> 2, sc = (tid & 3) << 4;

    #pragma unroll 1
    for (int c0 = 0; c0 < MOUT; c0 += 64) {
        f32x4 acc = {0.f, 0.f, 0.f, 0.f};
        const u16x8* wp = (const u16x8*)(Wg + (size_t)(c0 + sr) * KIN + sc);
        u16x8 w0 = wp[0], w1 = wp[1];
        #pragma unroll
        for (int k0 = 0; k0 < KIN; k0 += 64) {
            *(u16x8*)&wst[sr * 72 + sc]     = w0;
            *(u16x8*)&wst[sr * 72 + sc + 8] = w1;
            __syncthreads();
            if (k0 + 64 < KIN) {     // prefetch next tile, in flight over MFMA
                wp += 8; w0 = wp[0]; w1 = wp[1];
            }
            #pragma unroll
            for (int kt = 0; kt < 64; kt += 32) {
                bf16x8 af = *(const bf16x8*)&AL[l16 * LDA + k0 + kt + (quad << 3)];
                bf16x8 bf = *(const bf16x8*)&wst[((wave << 4) + l16) * 72 + kt + (quad << 3)];
                acc = __builtin_amdgcn_mfma_f32_16x16x32_bf16(af, bf, acc, 0, 0, 0);
            }
            __syncthreads();
        }
        // epilogue (C layout: col = lane&15 within tile, row = quad*4+r)
        int col = c0 + (wave << 4) + l16;
        if (MODE == M_Q || MODE == M_K || MODE == M_V) {
            int hh = col >> 5, d = col & 31;
            float bv = (MODE == M_K) ? bkG[col] : 0.f;
            #pragma unroll
            for (int r = 0; r < 4; r++) {
                int row = rowBase + (quad << 2) + r;
                if (row < S_ROWS) {
                    float v = acc[r] + bv;
                    if (MODE == M_Q) v *= 0.25506362f;   // 1/sqrt(32)*log2(e)
                    if (MODE == M_V)
                        qkvG[((size_t)hh * 32 + d) * 2048 + row] = f2b(v);
                    else
                        qkvG[((size_t)hh * 2048 + row) * 32 + d] = f2b(v);
                }
            }
        } else if (MODE == M_F32) {
            if (col < AFF_OUT) {
                float bv = biasG[col];
                #pragma unroll
                for (int r = 0; r < 4; r++)
                    hbL[((quad << 2) + r) * LDH + col] = acc[r] + bv;
            }
        } else {
            float bv = biasG ? biasG[col] : 0.f;
            #pragma unroll
            for (int r = 0; r < 4; r++) {
                int rowl = (quad << 2) + r;
                float v = acc[r] + bv;
                if (MODE == M_RES) { v += hbL[rowl * LDH + col]; hbL[rowl * LDH + col] = v; }
                if (MODE == M_HBI) { hbL[rowl * LDH + col] = v; }
                if (MODE == M_RELU) v = fmaxf(v, 0.f);
                OL[rowl * LDA + col] = f2b(v);
            }
        }
    }
    __syncthreads();
}

__device__ __forceinline__ void preload256(const unsigned short* G,
    unsigned short* B, int rowBase, int tid)
{
    int row = tid >> 4, c = (tid & 15) << 4;
    const unsigned short* g = G + (size_t)(rowBase + row) * 256 + c;
    *(u16x8*)&B[row * LDA + c]     = *(const u16x8*)(g);
    *(u16x8*)&B[row * LDA + c + 8] = *(const u16x8*)(g + 8);
}

__device__ __forceinline__ void preload_hbuf(const float* G, float* hbL,
    int rowBase, int tid)
{
    int row = tid >> 4, c = (tid & 15) << 4;
    const float* g = G + (size_t)(rowBase + row) * 256 + c;
    #pragma unroll
    for (int j = 0; j < 4; j++)
        *(float4*)&hbL[row * LDH + c + 4 * j] = *(const float4*)(g + 4 * j);
}

__device__ __forceinline__ void flush_hbuf(float* G, const float* hbL,
    int rowBase, int tid)
{
    int row = tid >> 4, c = (tid & 15) << 4;
    if (rowBase + row >= S_ROWS) return;
    float* g = G + (size_t)(rowBase + row) * 256 + c;
    #pragma unroll
    for (int j = 0; j < 4; j++)
        *(float4*)(g + 4 * j) = *(const float4*)&hbL[row * LDH + c + 4 * j];
}

// ---------------------------------------------------------------------------
// chainA: cond -> embed MLP -> hbuf/LDS -> QKV(layer 0). 128 blocks x 16 rows.
// ---------------------------------------------------------------------------
__global__ __launch_bounds__(256, 2) void chainA(Args a)
{
    __shared__ __align__(16) unsigned short buf0[16 * LDA];
    __shared__ __align__(16) unsigned short buf1[16 * LDA];
    __shared__ __align__(16) unsigned short wst[64 * 72];
    __shared__ __align__(16) float hbL[16 * LDH];
    int tid = threadIdx.x;
    int rowBase = blockIdx.x << 4;

    {   // preload cond (16 x 64)
        int row = tid >> 4, c = (tid & 15) << 2;
        *(u16x4*)&buf0[row * LDA + c] =
            *(const u16x4*)(a.cond + (size_t)(rowBase + row) * 64 + c);
    }
    __syncthreads();

    stage2<64,  512, M_RELU>(buf0, wst, a.wbp + OFF_EW0, a.e_b0, buf1, hbL, nullptr, nullptr, rowBase, tid);
    stage2<512, 512, M_RELU>(buf1, wst, a.wbp + OFF_EW1, a.e_b1, buf0, hbL, nullptr, nullptr, rowBase, tid);
    stage2<512, 256, M_HBI >(buf0, wst, a.wbp + OFF_EW2, a.e_b2, buf1, hbL, nullptr, nullptr, rowBase, tid);
    flush_hbuf(a.hbuf, hbL, rowBase, tid);
    stage2<256, 256, M_Q>(buf1, wst, a.wbp + OFF_WQ, nullptr, nullptr, hbL, a.qbh, nullptr, rowBase, tid);
    stage2<256, 256, M_K>(buf1, wst, a.wbp + OFF_WK, nullptr, nullptr, hbL, a.kbh, a.bk, rowBase, tid);
    stage2<256, 256, M_V>(buf1, wst, a.wbp + OFF_WV, nullptr, nullptr, hbL, a.vbT, nullptr, rowBase, tid);
}

// ---------------------------------------------------------------------------
// chainB(l): obb -> Wo(+res) -> MLP(+res) -> QKV(l+1)   (l<3)
//            l=3: ... -> aff MLP -> inline spline.      128 blocks x 16 rows.
// ---------------------------------------------------------------------------
__global__ __launch_bounds__(256, 2) void chainB(Args a, int l)
{
    __shared__ __align__(16) unsigned short buf0[16 * LDA];
    __shared__ __align__(16) unsigned short buf1[16 * LDA];
    __shared__ __align__(16) unsigned short wst[64 * 72];
    __shared__ __align__(16) float hbL[16 * LDH];
    int tid = threadIdx.x;
    int rowBase = blockIdx.x << 4;

    preload256(a.obb, buf0, rowBase, tid);
    preload_hbuf(a.hbuf, hbL, rowBase, tid);
    __syncthreads();

    stage2<256, 256, M_RES >(buf0, wst, a.wbp + OFF_WO  + l * 65536,  a.bo  + l * 256, buf1, hbL, nullptr, nullptr, rowBase, tid);
    stage2<256, 512, M_RELU>(buf1, wst, a.wbp + OFF_MW0 + l * 131072, a.mb0 + l * 512, buf0, hbL, nullptr, nullptr, rowBase, tid);
    stage2<512, 512, M_RELU>(buf0, wst, a.wbp + OFF_MW1 + l * 262144, a.mb1 + l * 512, buf1, hbL, nullptr, nullptr, rowBase, tid);
    stage2<512, 256, M_RES >(buf1, wst, a.wbp + OFF_MW2 + l * 131072, a.mb2 + l * 256, buf0, hbL, nullptr, nullptr, rowBase, tid);

    if (l < 3) {
        flush_hbuf(a.hbuf, hbL, rowBase, tid);
        int n = l + 1;
        if (n == 1) {
            stage2<256, 256, M_Q>(buf0, wst, a.wbp + OFF_WQ + 65536, nullptr, nullptr, hbL, a.qbh, nullptr, rowBase, tid);
            stage2<256, 256, M_K>(buf0, wst, a.wbp + OFF_WK + 65536, nullptr, nullptr, hbL, a.kbh, a.bk + 256, rowBase, tid);
            stage2<256, 256, M_V>(buf0, wst, a.wbp + OFF_WV + 65536, nullptr, nullptr, hbL, a.vbT, nullptr, rowBase, tid);
        } else if (n == 2) {
            stage2<256, 256, M_Q>(buf0, wst, a.wbp + OFF_WQ + 131072, nullptr, nullptr, hbL, a.qbh, nullptr, rowBase, tid);
            stage2<256, 256, M_K>(buf0, wst, a.wbp + OFF_WK + 131072, nullptr, nullptr, hbL, a.kbh, a.bk + 512, rowBase, tid);
            stage2<256, 256, M_V>(buf0, wst, a.wbp + OFF_WV + 131072, nullptr, nullptr, hbL, a.vbT, nullptr, rowBase, tid);
        } else {
            stage2<256, 256, M_Q>(buf0, wst, a.wbp + OFF_WQ + 196608, nullptr, nullptr, hbL, a.qbh, nullptr, rowBase, tid);
            stage2<256, 256, M_K>(buf0, wst, a.wbp + OFF_WK + 196608, nullptr, nullptr, hbL, a.kbh, a.bk + 768, rowBase, tid);
            stage2<256, 256, M_V>(buf0, wst, a.wbp + OFF_WV + 196608, nullptr, nullptr, hbL, a.vbT, nullptr, rowBase, tid);
        }
        return;
    }

    // affine-param MLP + inline spline (params land in hbL, f32)
    stage2<256, 512, M_RELU>(buf0, wst, a.wbp + OFF_AW0, a.a_b0, buf1, hbL, nullptr, nullptr, rowBase, tid);
    stage2<512, 512, M_RELU>(buf1, wst, a.wbp + OFF_AW1, a.a_b1, buf0, hbL, nullptr, nullptr, rowBase, tid);
    stage2<512, 64,  M_F32 >(buf0, wst, a.wbp + OFF_AW2, a.a_b2, buf1, hbL, nullptr, nullptr, rowBase, tid);
    __syncthreads();

    float ld = 0.f;
    if (tid < 16) {
        int r = rowBase + tid;
        if (r < S_ROWS) {
            const float* p = hbL + tid * LDH;
            float x = a.pos[(r + 1) * 3 + 2];
            float xc = fminf(fmaxf(x, 0.f), 1.f);

            float mw = -1e30f, mh = -1e30f;
            #pragma unroll
            for (int j = 0; j < NBINS; j++) {
                mw = fmaxf(mw, p[j]);
                mh = fmaxf(mh, p[NBINS + j]);
            }
            float sw = 0.f, sh = 0.f;
            #pragma unroll
            for (int j = 0; j < NBINS; j++) {
                sw += __expf(p[j] - mw);
                sh += __expf(p[NBINS + j] - mh);
            }
            const float span = 1.0f - NBINS * 1e-4f;
            float scw = span / sw, sch = span / sh;

            float cumw = 0.f, cumh = 0.f;
            float xk = 0.f, yk = 0.f, wk = 0.f, hk = 0.f;
            int k = 0;
            #pragma unroll
            for (int j = 0; j < NBINS; j++) {
                float wj = __expf(p[j] - mw) * scw + 1e-4f;
                float hj = __expf(p[NBINS + j] - mh) * sch + 1e-4f;
                if (xc >= cumw) { k = j; xk = cumw; yk = cumh; wk = wj; hk = hj; }
                cumw += wj; cumh += hj;
            }
            float offset = logf(expm1f(0.9999f));
            float t0 = p[2 * NBINS + k] + offset;
            float t1 = ((k == NBINS - 1) ? p[2 * NBINS] : p[2 * NBINS + k + 1]) + offset;
            float dk  = ((t0 > 15.f) ? t0 : log1pf(__expf(t0))) + 1e-4f;
            float dk1 = ((t1 > 15.f) ? t1 : log1pf(__expf(t1))) + 1e-4f;

            float sl = hk / wk;
            float z = (xc - xk) / wk;
            float z1 = 1.f - z;
            float den = sl + (dk1 + dk - 2.f * sl) * z * z1;
            float y = yk + hk * (sl * z * z + dk * z * z1) / den;
            float ldv = 2.f * logf(sl)
                      + logf(dk1 * z * z + 2.f * sl * z * z1 + dk * z1 * z1)
                      - 2.f * logf(den);
            bool inside = (x >= 0.f) && (x <= 1.f);
            y = inside ? y : x;
            ld = inside ? ldv : 0.f;
            a.out[(r + 1) * 3 + 2] = y;
        }
        ld += __shfl_down(ld, 8, 64);
        ld += __shfl_down(ld, 4, 64);
        ld += __shfl_down(ld, 2, 64);
        ld += __shfl_down(ld, 1, 64);
        if (tid == 0) atomicAdd(&a.out[6144], ld);
    }
}

// ---------------------------------------------------------------------------
// MFMA flash attention with in-block chunk combine (proven, unchanged).
// ---------------------------------------------------------------------------
__global__ __launch_bounds__(256) void attn_kernel(
    const unsigned short* __restrict__ qbh,
    const unsigned short* __restrict__ kbh,
    const unsigned short* __restrict__ vbT,
    unsigned short* __restrict__ obb)
{
    __shared__ __align__(16) float usmem[2 * 1088];
    int tid = threadIdx.x;
    int wave = tid >> 6, lane = tid & 63;
    int l31 = lane & 31, hf = lane >> 5;
    int u = blockIdx.x * 2 + (wave >> 1);
    int chunk = wave & 1;
    int qtile = u >> 3, h = u & 7;
    int q0 = qtile << 5;
    int kstart = chunk * 1024;
    int kend = chunk ? S_ROWS : 1024;

    const unsigned short* qp = qbh + ((size_t)h * 2048 + (q0 + l31)) * 32 + hf * 8;
    bf16x8 qf0 = *(const bf16x8*)(qp);
    bf16x8 qf1 = *(const bf16x8*)(qp + 16);
    const unsigned short* kb_h = kbh + (size_t)h * 2048 * 32;
    const unsigned short* vb_h = vbT + ((size_t)h * 32 + l31) * 2048;

    f32x16 acc = {};
    float m = -1e30f, l = 0.f;

    for (int key0 = kstart; key0 < kend; key0 += 32) {
        const unsigned short* kp = kb_h + (size_t)(key0 + l31) * 32 + hf * 8;
        bf16x8 kf0 = *(const bf16x8*)(kp);
        bf16x8 kf1 = *(const bf16x8*)(kp + 16);
        bf16x8 vf0 = *(const bf16x8*)(vb_h + key0 + hf * 8);
        bf16x8 vf1 = *(const bf16x8*)(vb_h + key0 + 16 + hf * 8);

        f32x16 sc = {};
        sc = __builtin_amdgcn_mfma_f32_32x32x16_bf16(kf0, qf0, sc, 0, 0, 0);
        sc = __builtin_amdgcn_mfma_f32_32x32x16_bf16(kf1, qf1, sc, 0, 0, 0);

        if (key0 + 32 > kend) {
            #pragma unroll
            for (int r = 0; r < 16; r++) {
                int kr = key0 + (r & 3) + 8 * (r >> 2) + 4 * hf;
                if (kr >= kend) sc[r] = -1e30f;
            }
        }
        float tmax = sc[0];
        #pragma unroll
        for (int r = 1; r < 16; r++) tmax = fmaxf(tmax, sc[r]);
        tmax = fmaxf(tmax, __shfl_xor(tmax, 32, 64));
        float mnew = fmaxf(m, tmax);
        float corr = __builtin_amdgcn_exp2f(m - mnew);
        m = mnew;
        float p[16];
        float ls = 0.f;
        #pragma unroll
        for (int r = 0; r < 16; r++) {
            p[r] = __builtin_amdgcn_exp2f(sc[r] - mnew);
            ls += p[r];
        }
        ls += __shfl_xor(ls, 32, 64);
        l = l * corr + ls;
        if (__ballot(corr != 1.0f)) {
            #pragma unroll
            for (int r = 0; r < 16; r++) acc[r] *= corr;
        }
        unsigned int pk[8];
        #pragma unroll
        for (int i = 0; i < 8; i++)
            pk[i] = __builtin_amdgcn_perm(__float_as_uint(p[2*i+1]),
                                          __float_as_uint(p[2*i]), 0x07060302u);
        unsigned int x[8];
        #pragma unroll
        for (int i = 0; i < 8; i++)
            x[i] = (unsigned int)__shfl_xor((int)pk[i], 32, 64);
        union { unsigned int uu[4]; bf16x8 v; } B1, B2;
        B1.uu[0] = hf ? x[2]  : pk[0];
        B1.uu[1] = hf ? x[3]  : pk[1];
        B1.uu[2] = hf ? pk[2] : x[0];
        B1.uu[3] = hf ? pk[3] : x[1];
        B2.uu[0] = hf ? x[6]  : pk[4];
        B2.uu[1] = hf ? x[7]  : pk[5];
        B2.uu[2] = hf ? pk[6] : x[4];
        B2.uu[3] = hf ? pk[7] : x[5];
        acc = __builtin_amdgcn_mfma_f32_32x32x16_bf16(vf0, B1.v, acc, 0, 0, 0);
        acc = __builtin_amdgcn_mfma_f32_32x32x16_bf16(vf1, B2.v, acc, 0, 0, 0);
    }

    float* ubase = usmem + (wave >> 1) * 1088;
    if (chunk) {
        #pragma unroll
        for (int r = 0; r < 16; r++) ubase[lane * 16 + r] = acc[r];
        if (!hf) { ubase[1024 + l31 * 2] = m; ubase[1024 + l31 * 2 + 1] = l; }
    }
    __syncthreads();
    if (!chunk) {
        float m1 = ubase[1024 + l31 * 2];
        float l1 = ubase[1024 + l31 * 2 + 1];
        float ms = fmaxf(m, m1);
        float w0 = __builtin_amdgcn_exp2f(m - ms);
        float w1 = __builtin_amdgcn_exp2f(m1 - ms);
        float inv = 1.f / (w0 * l + w1 * l1);
        unsigned short* op = obb + (size_t)(q0 + l31) * DIM + h * 32;
        #pragma unroll
        for (int g = 0; g < 4; g++) {
            u16x4 o4;
            #pragma unroll
            for (int j = 0; j < 4; j++) {
                int r = 4 * g + j;
                float v = (w0 * acc[r] + w1 * ubase[lane * 16 + r]) * inv;
                o4[j] = f2b(v);
            }
            *(u16x4*)(op + 8 * g + 4 * hf) = o4;
        }
    }
}

// ---------------------------------------------------------------------------
extern "C" void kernel_launch(void* const* d_in, const int* in_sizes, int n_in,
                              void* d_out, int out_size, void* d_ws, size_t ws_size,
                              hipStream_t stream)
{
    Args a;
    a.pos   = (const float*)d_in[0];
    a.scale = (const float*)d_in[1];
    a.press = (const float*)d_in[2];
    a.temp  = (const float*)d_in[3];
    a.e_w0  = (const float*)d_in[4];
    a.e_b0  = (const float*)d_in[5];
    a.wsrc[0] = (const float*)d_in[6];   // e_w1
    a.e_b1  = (const float*)d_in[7];
    a.wsrc[1] = (const float*)d_in[8];   // e_w2
    a.e_b2  = (const float*)d_in[9];
    a.wsrc[2] = (const float*)d_in[10];  // Wq
    a.wsrc[3] = (const float*)d_in[11];  // Wk
    a.bk    = (const float*)d_in[12];
    a.wsrc[4] = (const float*)d_in[13];  // Wv
    a.wsrc[5] = (const float*)d_in[14];  // Wo
    a.bo    = (const float*)d_in[15];
    a.wsrc[6] = (const float*)d_in[16];  // mw0
    a.mb0   = (const float*)d_in[17];
    a.wsrc[7] = (const float*)d_in[18];  // mw1
    a.mb1   = (const float*)d_in[19];
    a.wsrc[8] = (const float*)d_in[20];  // mw2
    a.mb2   = (const float*)d_in[21];
    a.wsrc[9] = (const float*)d_in[22];  // a_w0
    a.a_b0  = (const float*)d_in[23];
    a.wsrc[10] = (const float*)d_in[24]; // a_w1
    a.a_b1  = (const float*)d_in[25];
    a.wsrc[11] = (const float*)d_in[26]; // a_w2
    a.a_b2  = (const float*)d_in[27];
    a.out   = (float*)d_out;

    const size_t WB_U16 = (size_t)EW0P_N + W_MAIN;   // 3990016 u16
    float* ws = (float*)d_ws;
    size_t off = 0;
    a.hbuf = ws + off; off += 2048 * 256;
    a.wbp  = (unsigned short*)(ws + off); off += WB_U16 / 2;
    a.cond = (unsigned short*)(ws + off); off += 2048 * 64 / 2;  // pads wbp OOB reads
    a.obb  = (unsigned short*)(ws + off); off += 2048 * 256 / 2;
    a.qbh  = (unsigned short*)(ws + off); off += 8 * 2048 * 32 / 2;
    a.kbh  = (unsigned short*)(ws + off); off += 8 * 2048 * 32 / 2;
    a.vbT  = (unsigned short*)(ws + off); off += 8 * 2048 * 32 / 2;
    (void)ws_size;

    hipLaunchKernelGGL(setup_kernel, dim3(1024), dim3(256), 0, stream, a);
    hipLaunchKernelGGL(chainA, dim3(128), dim3(256), 0, stream, a);
    for (int l = 0; l < 4; l++) {
        hipLaunchKernelGGL(attn_kernel, dim3(256), dim3(256), 0, stream,
                           a.qbh, a.kbh, a.vbT, a.obb);
        hipLaunchKernelGGL(chainB, dim3(128), dim3(256), 0, stream, a, l);
    }
}

// Round 9
// 501.435 us; speedup vs baseline: 1.3667x; 1.3667x over previous
//
#include <hip/hip_runtime.h>
#include <math.h>

#define S_ROWS 2047
#define DIM 256
#define NBINS 16
#define AFF_OUT 49

typedef short bf16x8 __attribute__((ext_vector_type(8)));
typedef float f32x4 __attribute__((ext_vector_type(4)));
typedef float f32x16 __attribute__((ext_vector_type(16)));
typedef unsigned short u16x8 __attribute__((ext_vector_type(8)));
typedef unsigned short u16x4 __attribute__((ext_vector_type(4)));

__device__ __forceinline__ unsigned short f2b(float f) {
    unsigned int u = __float_as_uint(f);
    u += 0x7FFFu + ((u >> 16) & 1u);      // round-to-nearest-even
    return (unsigned short)(u >> 16);
}

// bf16 weight region (u16 offsets): [ew0 padded 512x64 | 12 segments]
#define W_MAIN 3957248
#define EW0P_N 32768
#define OFF_EW0 0
#define OFF_EW1 (EW0P_N + 0)
#define OFF_EW2 (EW0P_N + 262144)
#define OFF_WQ  (EW0P_N + 393216)
#define OFF_WK  (EW0P_N + 655360)
#define OFF_WV  (EW0P_N + 917504)
#define OFF_WO  (EW0P_N + 1179648)
#define OFF_MW0 (EW0P_N + 1441792)
#define OFF_MW1 (EW0P_N + 1966080)
#define OFF_MW2 (EW0P_N + 3014656)
#define OFF_AW0 (EW0P_N + 3538944)
#define OFF_AW1 (EW0P_N + 3670016)
#define OFF_AW2 (EW0P_N + 3932160)

struct Args {
    const float *pos, *scale, *press, *temp;
    const float *e_w0;
    const float *wsrc[12];
    const float *e_b0, *e_b1, *e_b2, *bk, *bo;
    const float *mb0, *mb1, *mb2, *a_b0, *a_b1, *a_b2;
    unsigned short *wbp, *cond, *obb, *qbh, *kbh, *vbT;
    float *hbuf, *out;
};

// ---------------------------------------------------------------------------
// setup (proven): weight f32->bf16 (+ew0 pad to K=64), cond embed, pos copy.
// ---------------------------------------------------------------------------
#define SP0 (W_MAIN / 4)
#define SP1 (SP0 + EW0P_N / 4)
#define SP2 (SP1 + 2048 * 64 / 4)
#define SP3 (SP2 + 1537)
__global__ __launch_bounds__(256) void setup_kernel(Args a)
{
    const int offs[13] = {0, 262144, 393216, 655360, 917504, 1179648, 1441792,
                          1966080, 3014656, 3538944, 3670016, 3932160, 3957248};
    for (int i4 = blockIdx.x * 256 + threadIdx.x; i4 < SP3;
         i4 += gridDim.x * 256) {
        if (i4 < SP0) {
            int e = i4 * 4;
            int s = 0;
            #pragma unroll
            for (int j = 1; j < 12; j++) s += (e >= offs[j]);
            const float4 v = *(const float4*)(a.wsrc[s] + (e - offs[s]));
            u16x4 o;
            o[0] = f2b(v.x); o[1] = f2b(v.y); o[2] = f2b(v.z); o[3] = f2b(v.w);
            *(u16x4*)(a.wbp + EW0P_N + e) = o;
        } else if (i4 < SP1) {
            int e = (i4 - SP0) * 4;
            u16x4 o;
            #pragma unroll
            for (int r = 0; r < 4; r++) {
                int ee = e + r;
                int row = ee >> 6, col = ee & 63;
                o[r] = (col < 35) ? f2b(a.e_w0[row * 35 + col]) : (unsigned short)0;
            }
            *(u16x4*)(a.wbp + e) = o;
        } else if (i4 < SP2) {
            int e = (i4 - SP1) * 4;
            int row = e >> 6;
            u16x4 o;
            #pragma unroll
            for (int r = 0; r < 4; r++) {
                int c = (e + r) & 63;
                float v = 0.f;
                if (row < S_ROWS) {
                    if (c < 32) {
                        int coord = c >> 4;
                        int w = c & 15;
                        float x = a.pos[(row + 1) * 3 + coord];
                        float f = 6.283185307179586f * (float)((w & 7) + 1);
                        v = (w < 8) ? cosf(x * f) : sinf(x * f);
                    } else if (c == 32) v = a.scale[0];
                    else if (c == 33) v = a.temp[0];
                    else if (c == 34) v = a.press[0];
                }
                o[r] = f2b(v);
            }
            *(u16x4*)(a.cond + e) = o;
        } else {
            int e = (i4 - SP2) * 4;
            #pragma unroll
            for (int r = 0; r < 4; r++) {
                int ee = e + r;
                if (ee < 6144) a.out[ee] = a.pos[ee];
                else if (ee == 6144) a.out[ee] = 0.f;
            }
        }
    }
}

// ---------------------------------------------------------------------------
// Chain stage v3: per 64-col group, ALL KT=KIN/64 weight K-tiles are loaded
// into registers up front (<=64 VGPR, all loads in flight together), then
// drained through LDS one tile per round. Latency exposed once per group,
// not once per round.
// ---------------------------------------------------------------------------
#define LDA 520        // u16 stride of LDS activation buffers
#define LDH 260        // f32 stride of LDS residual buffer
#define M_RELU 0
#define M_HBI  1       // hbL = v; OL = bf16(v)
#define M_RES  2       // v += hbL; hbL = v; OL = bf16(v)
#define M_Q    3
#define M_K    4
#define M_V    5
#define M_F32  6       // f32 -> hbL (spline params), guard col < 49

template<int KIN, int MOUT, int MODE>
__device__ __forceinline__ void stage3(
    const unsigned short* __restrict__ AL, unsigned short* __restrict__ wst,
    const unsigned short* __restrict__ Wg, const float* __restrict__ biasG,
    unsigned short* __restrict__ OL, float* __restrict__ hbL,
    unsigned short* __restrict__ qkvG, const float* __restrict__ bkG,
    int rowBase, int tid)
{
    constexpr int KT = KIN / 64;                 // 1, 4 or 8
    int wave = tid >> 6, lane = tid & 63, quad = lane >> 4, l16 = lane & 15;
    int sr = tid >> 2, sc = (tid & 3) << 4;

    #pragma unroll 1
    for (int c0 = 0; c0 < MOUT; c0 += 64) {
        // issue ALL weight loads for this 64-col group (KT*2 loads in flight)
        const u16x8* wp = (const u16x8*)(Wg + (size_t)(c0 + sr) * KIN + sc);
        u16x8 w0[KT], w1[KT];
        #pragma unroll
        for (int t = 0; t < KT; t++) { w0[t] = wp[t * 8]; w1[t] = wp[t * 8 + 1]; }

        f32x4 acc = {0.f, 0.f, 0.f, 0.f};
        #pragma unroll
        for (int t = 0; t < KT; t++) {
            *(u16x8*)&wst[sr * 72 + sc]     = w0[t];
            *(u16x8*)&wst[sr * 72 + sc + 8] = w1[t];
            __syncthreads();
            #pragma unroll
            for (int kt = 0; kt < 64; kt += 32) {
                bf16x8 af = *(const bf16x8*)&AL[l16 * LDA + t * 64 + kt + (quad << 3)];
                bf16x8 bf = *(const bf16x8*)&wst[((wave << 4) + l16) * 72 + kt + (quad << 3)];
                acc = __builtin_amdgcn_mfma_f32_16x16x32_bf16(af, bf, acc, 0, 0, 0);
            }
            __syncthreads();
        }
        // epilogue (C layout: col = lane&15 within wave strip, row = quad*4+r)
        int col = c0 + (wave << 4) + l16;
        if (MODE == M_Q || MODE == M_K || MODE == M_V) {
            int hh = col >> 5, d = col & 31;
            float bv = (MODE == M_K) ? bkG[col] : 0.f;
            #pragma unroll
            for (int r = 0; r < 4; r++) {
                int row = rowBase + (quad << 2) + r;
                if (row < S_ROWS) {
                    float v = acc[r] + bv;
                    if (MODE == M_Q) v *= 0.25506362f;   // 1/sqrt(32)*log2(e)
                    if (MODE == M_V)
                        qkvG[((size_t)hh * 32 + d) * 2048 + row] = f2b(v);
                    else
                        qkvG[((size_t)hh * 2048 + row) * 32 + d] = f2b(v);
                }
            }
        } else if (MODE == M_F32) {
            if (col < AFF_OUT) {
                float bv = biasG[col];
                #pragma unroll
                for (int r = 0; r < 4; r++)
                    hbL[((quad << 2) + r) * LDH + col] = acc[r] + bv;
            }
        } else {
            float bv = biasG ? biasG[col] : 0.f;
            #pragma unroll
            for (int r = 0; r < 4; r++) {
                int rowl = (quad << 2) + r;
                float v = acc[r] + bv;
                if (MODE == M_RES) { v += hbL[rowl * LDH + col]; hbL[rowl * LDH + col] = v; }
                if (MODE == M_HBI) { hbL[rowl * LDH + col] = v; }
                if (MODE == M_RELU) v = fmaxf(v, 0.f);
                OL[rowl * LDA + col] = f2b(v);
            }
        }
    }
    __syncthreads();
}

__device__ __forceinline__ void preload256(const unsigned short* G,
    unsigned short* B, int rowBase, int tid)
{
    int row = tid >> 4, c = (tid & 15) << 4;
    const unsigned short* g = G + (size_t)(rowBase + row) * 256 + c;
    *(u16x8*)&B[row * LDA + c]     = *(const u16x8*)(g);
    *(u16x8*)&B[row * LDA + c + 8] = *(const u16x8*)(g + 8);
}

__device__ __forceinline__ void preload_hbuf(const float* G, float* hbL,
    int rowBase, int tid)
{
    int row = tid >> 4, c = (tid & 15) << 4;
    const float* g = G + (size_t)(rowBase + row) * 256 + c;
    #pragma unroll
    for (int j = 0; j < 4; j++)
        *(float4*)&hbL[row * LDH + c + 4 * j] = *(const float4*)(g + 4 * j);
}

__device__ __forceinline__ void flush_hbuf(float* G, const float* hbL,
    int rowBase, int tid)
{
    int row = tid >> 4, c = (tid & 15) << 4;
    if (rowBase + row >= S_ROWS) return;
    float* g = G + (size_t)(rowBase + row) * 256 + c;
    #pragma unroll
    for (int j = 0; j < 4; j++)
        *(float4*)(g + 4 * j) = *(const float4*)&hbL[row * LDH + c + 4 * j];
}

// ---------------------------------------------------------------------------
// chainA: cond -> embed MLP -> hbuf/LDS -> QKV(layer 0). 128 blocks x 16 rows.
// ---------------------------------------------------------------------------
__global__ __launch_bounds__(256, 2) void chainA(Args a)
{
    __shared__ __align__(16) unsigned short buf0[16 * LDA];
    __shared__ __align__(16) unsigned short buf1[16 * LDA];
    __shared__ __align__(16) unsigned short wst[64 * 72];
    __shared__ __align__(16) float hbL[16 * LDH];
    int tid = threadIdx.x;
    int rowBase = blockIdx.x << 4;

    {   // preload cond (16 x 64)
        int row = tid >> 4, c = (tid & 15) << 2;
        *(u16x4*)&buf0[row * LDA + c] =
            *(const u16x4*)(a.cond + (size_t)(rowBase + row) * 64 + c);
    }
    __syncthreads();

    stage3<64,  512, M_RELU>(buf0, wst, a.wbp + OFF_EW0, a.e_b0, buf1, hbL, nullptr, nullptr, rowBase, tid);
    stage3<512, 512, M_RELU>(buf1, wst, a.wbp + OFF_EW1, a.e_b1, buf0, hbL, nullptr, nullptr, rowBase, tid);
    stage3<512, 256, M_HBI >(buf0, wst, a.wbp + OFF_EW2, a.e_b2, buf1, hbL, nullptr, nullptr, rowBase, tid);
    flush_hbuf(a.hbuf, hbL, rowBase, tid);
    stage3<256, 256, M_Q>(buf1, wst, a.wbp + OFF_WQ, nullptr, nullptr, hbL, a.qbh, nullptr, rowBase, tid);
    stage3<256, 256, M_K>(buf1, wst, a.wbp + OFF_WK, nullptr, nullptr, hbL, a.kbh, a.bk, rowBase, tid);
    stage3<256, 256, M_V>(buf1, wst, a.wbp + OFF_WV, nullptr, nullptr, hbL, a.vbT, nullptr, rowBase, tid);
}

// ---------------------------------------------------------------------------
// chainB(l): obb -> Wo(+res) -> MLP(+res) -> QKV(l+1)   (l<3)
//            l=3: ... -> aff MLP -> inline spline.      128 blocks x 16 rows.
// ---------------------------------------------------------------------------
__global__ __launch_bounds__(256, 2) void chainB(Args a, int l)
{
    __shared__ __align__(16) unsigned short buf0[16 * LDA];
    __shared__ __align__(16) unsigned short buf1[16 * LDA];
    __shared__ __align__(16) unsigned short wst[64 * 72];
    __shared__ __align__(16) float hbL[16 * LDH];
    int tid = threadIdx.x;
    int rowBase = blockIdx.x << 4;

    preload256(a.obb, buf0, rowBase, tid);
    preload_hbuf(a.hbuf, hbL, rowBase, tid);
    __syncthreads();

    stage3<256, 256, M_RES >(buf0, wst, a.wbp + OFF_WO  + l * 65536,  a.bo  + l * 256, buf1, hbL, nullptr, nullptr, rowBase, tid);
    stage3<256, 512, M_RELU>(buf1, wst, a.wbp + OFF_MW0 + l * 131072, a.mb0 + l * 512, buf0, hbL, nullptr, nullptr, rowBase, tid);
    stage3<512, 512, M_RELU>(buf0, wst, a.wbp + OFF_MW1 + l * 262144, a.mb1 + l * 512, buf1, hbL, nullptr, nullptr, rowBase, tid);
    stage3<512, 256, M_RES >(buf1, wst, a.wbp + OFF_MW2 + l * 131072, a.mb2 + l * 256, buf0, hbL, nullptr, nullptr, rowBase, tid);

    if (l < 3) {
        flush_hbuf(a.hbuf, hbL, rowBase, tid);
        int n = l + 1;
        if (n == 1) {
            stage3<256, 256, M_Q>(buf0, wst, a.wbp + OFF_WQ + 65536, nullptr, nullptr, hbL, a.qbh, nullptr, rowBase, tid);
            stage3<256, 256, M_K>(buf0, wst, a.wbp + OFF_WK + 65536, nullptr, nullptr, hbL, a.kbh, a.bk + 256, rowBase, tid);
            stage3<256, 256, M_V>(buf0, wst, a.wbp + OFF_WV + 65536, nullptr, nullptr, hbL, a.vbT, nullptr, rowBase, tid);
        } else if (n == 2) {
            stage3<256, 256, M_Q>(buf0, wst, a.wbp + OFF_WQ + 131072, nullptr, nullptr, hbL, a.qbh, nullptr, rowBase, tid);
            stage3<256, 256, M_K>(buf0, wst, a.wbp + OFF_WK + 131072, nullptr, nullptr, hbL, a.kbh, a.bk + 512, rowBase, tid);
            stage3<256, 256, M_V>(buf0, wst, a.wbp + OFF_WV + 131072, nullptr, nullptr, hbL, a.vbT, nullptr, rowBase, tid);
        } else {
            stage3<256, 256, M_Q>(buf0, wst, a.wbp + OFF_WQ + 196608, nullptr, nullptr, hbL, a.qbh, nullptr, rowBase, tid);
            stage3<256, 256, M_K>(buf0, wst, a.wbp + OFF_WK + 196608, nullptr, nullptr, hbL, a.kbh, a.bk + 768, rowBase, tid);
            stage3<256, 256, M_V>(buf0, wst, a.wbp + OFF_WV + 196608, nullptr, nullptr, hbL, a.vbT, nullptr, rowBase, tid);
        }
        return;
    }

    // affine-param MLP + inline spline (params land in hbL, f32)
    stage3<256, 512, M_RELU>(buf0, wst, a.wbp + OFF_AW0, a.a_b0, buf1, hbL, nullptr, nullptr, rowBase, tid);
    stage3<512, 512, M_RELU>(buf1, wst, a.wbp + OFF_AW1, a.a_b1, buf0, hbL, nullptr, nullptr, rowBase, tid);
    stage3<512, 64,  M_F32 >(buf0, wst, a.wbp + OFF_AW2, a.a_b2, buf1, hbL, nullptr, nullptr, rowBase, tid);
    __syncthreads();

    float ld = 0.f;
    if (tid < 16) {
        int r = rowBase + tid;
        if (r < S_ROWS) {
            const float* p = hbL + tid * LDH;
            float x = a.pos[(r + 1) * 3 + 2];
            float xc = fminf(fmaxf(x, 0.f), 1.f);

            float mw = -1e30f, mh = -1e30f;
            #pragma unroll
            for (int j = 0; j < NBINS; j++) {
                mw = fmaxf(mw, p[j]);
                mh = fmaxf(mh, p[NBINS + j]);
            }
            float sw = 0.f, sh = 0.f;
            #pragma unroll
            for (int j = 0; j < NBINS; j++) {
                sw += __expf(p[j] - mw);
                sh += __expf(p[NBINS + j] - mh);
            }
            const float span = 1.0f - NBINS * 1e-4f;
            float scw = span / sw, sch = span / sh;

            float cumw = 0.f, cumh = 0.f;
            float xk = 0.f, yk = 0.f, wk = 0.f, hk = 0.f;
            int k = 0;
            #pragma unroll
            for (int j = 0; j < NBINS; j++) {
                float wj = __expf(p[j] - mw) * scw + 1e-4f;
                float hj = __expf(p[NBINS + j] - mh) * sch + 1e-4f;
                if (xc >= cumw) { k = j; xk = cumw; yk = cumh; wk = wj; hk = hj; }
                cumw += wj; cumh += hj;
            }
            float offset = logf(expm1f(0.9999f));
            float t0 = p[2 * NBINS + k] + offset;
            float t1 = ((k == NBINS - 1) ? p[2 * NBINS] : p[2 * NBINS + k + 1]) + offset;
            float dk  = ((t0 > 15.f) ? t0 : log1pf(__expf(t0))) + 1e-4f;
            float dk1 = ((t1 > 15.f) ? t1 : log1pf(__expf(t1))) + 1e-4f;

            float sl = hk / wk;
            float z = (xc - xk) / wk;
            float z1 = 1.f - z;
            float den = sl + (dk1 + dk - 2.f * sl) * z * z1;
            float y = yk + hk * (sl * z * z + dk * z * z1) / den;
            float ldv = 2.f * logf(sl)
                      + logf(dk1 * z * z + 2.f * sl * z * z1 + dk * z1 * z1)
                      - 2.f * logf(den);
            bool inside = (x >= 0.f) && (x <= 1.f);
            y = inside ? y : x;
            ld = inside ? ldv : 0.f;
            a.out[(r + 1) * 3 + 2] = y;
        }
        ld += __shfl_down(ld, 8, 64);
        ld += __shfl_down(ld, 4, 64);
        ld += __shfl_down(ld, 2, 64);
        ld += __shfl_down(ld, 1, 64);
        if (tid == 0) atomicAdd(&a.out[6144], ld);
    }
}

// ---------------------------------------------------------------------------
// MFMA flash attention with in-block chunk combine (proven, unchanged).
// ---------------------------------------------------------------------------
__global__ __launch_bounds__(256) void attn_kernel(
    const unsigned short* __restrict__ qbh,
    const unsigned short* __restrict__ kbh,
    const unsigned short* __restrict__ vbT,
    unsigned short* __restrict__ obb)
{
    __shared__ __align__(16) float usmem[2 * 1088];
    int tid = threadIdx.x;
    int wave = tid >> 6, lane = tid & 63;
    int l31 = lane & 31, hf = lane >> 5;
    int u = blockIdx.x * 2 + (wave >> 1);
    int chunk = wave & 1;
    int qtile = u >> 3, h = u & 7;
    int q0 = qtile << 5;
    int kstart = chunk * 1024;
    int kend = chunk ? S_ROWS : 1024;

    const unsigned short* qp = qbh + ((size_t)h * 2048 + (q0 + l31)) * 32 + hf * 8;
    bf16x8 qf0 = *(const bf16x8*)(qp);
    bf16x8 qf1 = *(const bf16x8*)(qp + 16);
    const unsigned short* kb_h = kbh + (size_t)h * 2048 * 32;
    const unsigned short* vb_h = vbT + ((size_t)h * 32 + l31) * 2048;

    f32x16 acc = {};
    float m = -1e30f, l = 0.f;

    for (int key0 = kstart; key0 < kend; key0 += 32) {
        const unsigned short* kp = kb_h + (size_t)(key0 + l31) * 32 + hf * 8;
        bf16x8 kf0 = *(const bf16x8*)(kp);
        bf16x8 kf1 = *(const bf16x8*)(kp + 16);
        bf16x8 vf0 = *(const bf16x8*)(vb_h + key0 + hf * 8);
        bf16x8 vf1 = *(const bf16x8*)(vb_h + key0 + 16 + hf * 8);

        f32x16 sc = {};
        sc = __builtin_amdgcn_mfma_f32_32x32x16_bf16(kf0, qf0, sc, 0, 0, 0);
        sc = __builtin_amdgcn_mfma_f32_32x32x16_bf16(kf1, qf1, sc, 0, 0, 0);

        if (key0 + 32 > kend) {
            #pragma unroll
            for (int r = 0; r < 16; r++) {
                int kr = key0 + (r & 3) + 8 * (r >> 2) + 4 * hf;
                if (kr >= kend) sc[r] = -1e30f;
            }
        }
        float tmax = sc[0];
        #pragma unroll
        for (int r = 1; r < 16; r++) tmax = fmaxf(tmax, sc[r]);
        tmax = fmaxf(tmax, __shfl_xor(tmax, 32, 64));
        float mnew = fmaxf(m, tmax);
        float corr = __builtin_amdgcn_exp2f(m - mnew);
        m = mnew;
        float p[16];
        float ls = 0.f;
        #pragma unroll
        for (int r = 0; r < 16; r++) {
            p[r] = __builtin_amdgcn_exp2f(sc[r] - mnew);
            ls += p[r];
        }
        ls += __shfl_xor(ls, 32, 64);
        l = l * corr + ls;
        if (__ballot(corr != 1.0f)) {
            #pragma unroll
            for (int r = 0; r < 16; r++) acc[r] *= corr;
        }
        unsigned int pk[8];
        #pragma unroll
        for (int i = 0; i < 8; i++)
            pk[i] = __builtin_amdgcn_perm(__float_as_uint(p[2*i+1]),
                                          __float_as_uint(p[2*i]), 0x07060302u);
        unsigned int x[8];
        #pragma unroll
        for (int i = 0; i < 8; i++)
            x[i] = (unsigned int)__shfl_xor((int)pk[i], 32, 64);
        union { unsigned int uu[4]; bf16x8 v; } B1, B2;
        B1.uu[0] = hf ? x[2]  : pk[0];
        B1.uu[1] = hf ? x[3]  : pk[1];
        B1.uu[2] = hf ? pk[2] : x[0];
        B1.uu[3] = hf ? pk[3] : x[1];
        B2.uu[0] = hf ? x[6]  : pk[4];
        B2.uu[1] = hf ? x[7]  : pk[5];
        B2.uu[2] = hf ? pk[6] : x[4];
        B2.uu[3] = hf ? pk[7] : x[5];
        acc = __builtin_amdgcn_mfma_f32_32x32x16_bf16(vf0, B1.v, acc, 0, 0, 0);
        acc = __builtin_amdgcn_mfma_f32_32x32x16_bf16(vf1, B2.v, acc, 0, 0, 0);
    }

    float* ubase = usmem + (wave >> 1) * 1088;
    if (chunk) {
        #pragma unroll
        for (int r = 0; r < 16; r++) ubase[lane * 16 + r] = acc[r];
        if (!hf) { ubase[1024 + l31 * 2] = m; ubase[1024 + l31 * 2 + 1] = l; }
    }
    __syncthreads();
    if (!chunk) {
        float m1 = ubase[1024 + l31 * 2];
        float l1 = ubase[1024 + l31 * 2 + 1];
        float ms = fmaxf(m, m1);
        float w0 = __builtin_amdgcn_exp2f(m - ms);
        float w1 = __builtin_amdgcn_exp2f(m1 - ms);
        float inv = 1.f / (w0 * l + w1 * l1);
        unsigned short* op = obb + (size_t)(q0 + l31) * DIM + h * 32;
        #pragma unroll
        for (int g = 0; g < 4; g++) {
            u16x4 o4;
            #pragma unroll
            for (int j = 0; j < 4; j++) {
                int r = 4 * g + j;
                float v = (w0 * acc[r] + w1 * ubase[lane * 16 + r]) * inv;
                o4[j] = f2b(v);
            }
            *(u16x4*)(op + 8 * g + 4 * hf) = o4;
        }
    }
}

// ---------------------------------------------------------------------------
extern "C" void kernel_launch(void* const* d_in, const int* in_sizes, int n_in,
                              void* d_out, int out_size, void* d_ws, size_t ws_size,
                              hipStream_t stream)
{
    Args a;
    a.pos   = (const float*)d_in[0];
    a.scale = (const float*)d_in[1];
    a.press = (const float*)d_in[2];
    a.temp  = (const float*)d_in[3];
    a.e_w0  = (const float*)d_in[4];
    a.e_b0  = (const float*)d_in[5];
    a.wsrc[0] = (const float*)d_in[6];   // e_w1
    a.e_b1  = (const float*)d_in[7];
    a.wsrc[1] = (const float*)d_in[8];   // e_w2
    a.e_b2  = (const float*)d_in[9];
    a.wsrc[2] = (const float*)d_in[10];  // Wq
    a.wsrc[3] = (const float*)d_in[11];  // Wk
    a.bk    = (const float*)d_in[12];
    a.wsrc[4] = (const float*)d_in[13];  // Wv
    a.wsrc[5] = (const float*)d_in[14];  // Wo
    a.bo    = (const float*)d_in[15];
    a.wsrc[6] = (const float*)d_in[16];  // mw0
    a.mb0   = (const float*)d_in[17];
    a.wsrc[7] = (const float*)d_in[18];  // mw1
    a.mb1   = (const float*)d_in[19];
    a.wsrc[8] = (const float*)d_in[20];  // mw2
    a.mb2   = (const float*)d_in[21];
    a.wsrc[9] = (const float*)d_in[22];  // a_w0
    a.a_b0  = (const float*)d_in[23];
    a.wsrc[10] = (const float*)d_in[24]; // a_w1
    a.a_b1  = (const float*)d_in[25];
    a.wsrc[11] = (const float*)d_in[26]; // a_w2
    a.a_b2  = (const float*)d_in[27];
    a.out   = (float*)d_out;

    const size_t WB_U16 = (size_t)EW0P_N + W_MAIN;   // 3990016 u16
    float* ws = (float*)d_ws;
    size_t off = 0;
    a.hbuf = ws + off; off += 2048 * 256;
    a.wbp  = (unsigned short*)(ws + off); off += WB_U16 / 2;
    a.cond = (unsigned short*)(ws + off); off += 2048 * 64 / 2;  // pads wbp OOB reads
    a.obb  = (unsigned short*)(ws + off); off += 2048 * 256 / 2;
    a.qbh  = (unsigned short*)(ws + off); off += 8 * 2048 * 32 / 2;
    a.kbh  = (unsigned short*)(ws + off); off += 8 * 2048 * 32 / 2;
    a.vbT  = (unsigned short*)(ws + off); off += 8 * 2048 * 32 / 2;
    (void)ws_size;

    hipLaunchKernelGGL(setup_kernel, dim3(1024), dim3(256), 0, stream, a);
    hipLaunchKernelGGL(chainA, dim3(128), dim3(256), 0, stream, a);
    for (int l = 0; l < 4; l++) {
        hipLaunchKernelGGL(attn_kernel, dim3(256), dim3(256), 0, stream,
                           a.qbh, a.kbh, a.vbT, a.obb);
        hipLaunchKernelGGL(chainB, dim3(128), dim3(256), 0, stream, a, l);
    }
}